// Round 5
// baseline (206.214 us; speedup 1.0000x reference)
//
#include <hip/hip_runtime.h>
#include <math.h>

#define SA_N   8192
#define SA_IN  512
#define SA_D   64
#define G_SPL  16

typedef short s16x8 __attribute__((ext_vector_type(8)));
typedef float f32x16 __attribute__((ext_vector_type(16)));

#define MFMA32(A, B, C) __builtin_amdgcn_mfma_f32_32x32x16_bf16((A), (B), (C), 0, 0, 0)

static __device__ __forceinline__ unsigned short f2bf_rn(float x) {
    unsigned int u = __float_as_uint(x);
    unsigned int r = (u + 0x7FFFu + ((u >> 16) & 1u)) >> 16;
    return (unsigned short)r;
}

static __device__ __forceinline__ void trunc_split(float f, unsigned short* hi, unsigned short* lo) {
    unsigned int u = __float_as_uint(f);
    *hi = (unsigned short)(u >> 16);
    float lf = f - __uint_as_float(u & 0xFFFF0000u);
    *lo = (unsigned short)(__float_as_uint(lf) >> 16);
}

static __device__ __forceinline__ void split8(const float4 a, const float4 b, s16x8* xh, s16x8* xl) {
    union { unsigned int u[4]; s16x8 v; } H, L;
    const float f[8] = {a.x, a.y, a.z, a.w, b.x, b.y, b.z, b.w};
#pragma unroll
    for (int p = 0; p < 4; ++p) {
        const unsigned int u0 = __float_as_uint(f[2 * p]);
        const unsigned int u1 = __float_as_uint(f[2 * p + 1]);
        H.u[p] = (u0 >> 16) | (u1 & 0xFFFF0000u);
        const float l0 = f[2 * p]     - __uint_as_float(u0 & 0xFFFF0000u);
        const float l1 = f[2 * p + 1] - __uint_as_float(u1 & 0xFFFF0000u);
        L.u[p] = (__float_as_uint(l0) >> 16) | (__float_as_uint(l1) & 0xFFFF0000u);
    }
    *xh = H.v; *xl = L.v;
}

// ---- Kernel 0: W (fp32) -> A-fragment-ordered bf16 hi/lo ----
__global__ __launch_bounds__(256) void wconv_kernel(
    const float* __restrict__ Wq, const float* __restrict__ Wk, const float* __restrict__ Wv,
    unsigned short* __restrict__ WHI, unsigned short* __restrict__ WLO)
{
    const int idx  = blockIdx.x * 256 + threadIdx.x;
    const int mat  = idx >> 15;
    const int rem  = idx & 32767;
    const int mt   = rem >> 14;
    const int ks   = (rem >> 9) & 31;
    const int lane = (rem >> 3) & 63;
    const int i    = rem & 7;
    const int o = mt * 32 + (lane & 31);
    const int k = ks * 16 + (lane >> 5) * 8 + i;
    const float* W = (mat == 0) ? Wq : (mat == 1 ? Wk : Wv);
    unsigned short hi, lo;
    trunc_split(W[o * SA_IN + k], &hi, &lo);
    WHI[idx] = hi; WLO[idx] = lo;
}

// ---- Kernel A: QKV via bf16x3 MFMA, 8 waves, 8-way k-split ----
// grid 256, block 512. Block = 32 rows (tile jt). Wave w handles ks = w*4..w*4+3.
// x-loads: per (row, ks) the h=0/h=1 lanes consume one full 64B line — no over-fetch.
// Epilogue: 8-partial LDS combine per output set, bias, fragment-order scatter.
__global__ __launch_bounds__(512, 2) void qkv_kernel(
    const float* __restrict__ in,
    const unsigned short* __restrict__ WHI, const unsigned short* __restrict__ WLO,
    const float* __restrict__ bq, const float* __restrict__ bk, const float* __restrict__ bv,
    unsigned short* __restrict__ Qhi, unsigned short* __restrict__ Qlo,
    unsigned short* __restrict__ KhiF, unsigned short* __restrict__ KloF,
    unsigned short* __restrict__ VF)
{
    __shared__ float cbuf[8][64][20];   // 40 KB
    const int t    = threadIdx.x;
    const int w    = t >> 6;        // 0..7
    const int lane = t & 63;
    const int h    = lane >> 5;
    const int q32  = lane & 31;
    const int jt   = blockIdx.x;
    const int rows0 = jt * 32;

    const s16x8* WH8 = (const s16x8*)WHI;
    const s16x8* WL8 = (const s16x8*)WLO;

    f32x16 acc[6] = {};   // q0,q1,k0,k1,v0,v1

#pragma unroll
    for (int ksl = 0; ksl < 4; ++ksl) {
        const int ks = (w << 2) + ksl;
        const float* xp = in + (size_t)(rows0 + q32) * SA_IN + ks * 16 + h * 8;
        const float4 xa = *(const float4*)xp;
        const float4 xb = *(const float4*)(xp + 4);
        s16x8 xh, xl;
        split8(xa, xb, &xh, &xl);
        const int fb = ks * 64 + lane;
#pragma unroll
        for (int mt = 0; mt < 2; ++mt) {
            s16x8 ah = WH8[(0 + mt) * 2048 + fb];
            s16x8 al = WL8[(0 + mt) * 2048 + fb];
            acc[mt] = MFMA32(ah, xh, acc[mt]);
            acc[mt] = MFMA32(ah, xl, acc[mt]);
            acc[mt] = MFMA32(al, xh, acc[mt]);
            ah = WH8[(2 + mt) * 2048 + fb];
            al = WL8[(2 + mt) * 2048 + fb];
            acc[2 + mt] = MFMA32(ah, xh, acc[2 + mt]);
            acc[2 + mt] = MFMA32(ah, xl, acc[2 + mt]);
            acc[2 + mt] = MFMA32(al, xh, acc[2 + mt]);
            ah = WH8[(4 + mt) * 2048 + fb];
            acc[4 + mt] = MFMA32(ah, xh, acc[4 + mt]);   // v: 1-term suffices
        }
    }

#pragma unroll
    for (int s = 0; s < 6; ++s) {
        __syncthreads();
#pragma unroll
        for (int rg = 0; rg < 4; ++rg) {
            float4 vv = { acc[s][4 * rg + 0], acc[s][4 * rg + 1],
                          acc[s][4 * rg + 2], acc[s][4 * rg + 3] };
            *(float4*)&cbuf[w][lane][4 * rg] = vv;
        }
        __syncthreads();
        if (w == s) {
            const int mat = s >> 1;
            const int mt  = s & 1;
            float c[16];
#pragma unroll
            for (int rg = 0; rg < 4; ++rg) {
                float4 acc4 = *(const float4*)&cbuf[0][lane][4 * rg];
#pragma unroll
                for (int p = 1; p < 8; ++p) {
                    const float4 pp = *(const float4*)&cbuf[p][lane][4 * rg];
                    acc4.x += pp.x; acc4.y += pp.y; acc4.z += pp.z; acc4.w += pp.w;
                }
                c[4 * rg + 0] = acc4.x; c[4 * rg + 1] = acc4.y;
                c[4 * rg + 2] = acc4.z; c[4 * rg + 3] = acc4.w;
            }
            const float* B = (mat == 0) ? bq : (mat == 1 ? bk : bv);
#pragma unroll
            for (int r = 0; r < 16; ++r) {
                const int o = mt * 32 + (r & 3) + 8 * (r >> 2) + 4 * h;
                const float val = c[r] + B[o];
                if (mat == 0) {
                    unsigned short hi, lo;
                    trunc_split(val, &hi, &lo);
                    Qhi[(size_t)(rows0 + q32) * 64 + o] = hi;
                    Qlo[(size_t)(rows0 + q32) * 64 + o] = lo;
                } else if (mat == 1) {
                    unsigned short hi, lo;
                    trunc_split(val, &hi, &lo);
                    const int kidx = ((jt * 4 + (o >> 4)) * 64 + ((o >> 3) & 1) * 32 + q32) * 8 + (o & 7);
                    KhiF[kidx] = hi;
                    KloF[kidx] = lo;
                } else {
                    const int vidx = ((jt * 4 + (o >> 5) * 2 + ((q32 >> 4) & 1)) * 64
                                      + ((q32 >> 3) & 1) * 32 + (o & 31)) * 8 + (q32 & 7);
                    VF[vidx] = f2bf_rn(val);
                }
            }
        }
    }
}

// ---- Kernel B: MFMA flash attention, key-split G=16 ----
// grid 1024 = 64 qb x 16 g; 4 blocks/CU (launch_bounds 256,4). Zero LDS, no barriers.
// g = blockIdx&15 with XCD = blockIdx%8 => each XCD L2 serves only 2 key-splits.
__global__ __launch_bounds__(256, 4) void attn_kernel(
    const unsigned short* __restrict__ Qhi, const unsigned short* __restrict__ Qlo,
    const unsigned short* __restrict__ KhiF, const unsigned short* __restrict__ KloF,
    const unsigned short* __restrict__ VF,
    unsigned short* __restrict__ Opart, float* __restrict__ Lpart)
{
    const int t    = threadIdx.x;
    const int w    = t >> 6;
    const int lane = t & 63;
    const int h    = lane >> 5;
    const int q32  = lane & 31;
    const int qb   = blockIdx.x >> 4;
    const int g    = blockIdx.x & 15;
    const int q0   = (qb * 4 + w) * 32;

    s16x8 qh[4], ql[4];
#pragma unroll
    for (int s = 0; s < 4; ++s) {
        const size_t off = (size_t)(q0 + q32) * 64 + s * 16 + h * 8;
        qh[s] = *reinterpret_cast<const s16x8*>(Qhi + off);
        ql[s] = *reinterpret_cast<const s16x8*>(Qlo + off);
    }

    const s16x8* KH = reinterpret_cast<const s16x8*>(KhiF);
    const s16x8* KL = reinterpret_cast<const s16x8*>(KloF);
    const s16x8* VV = reinterpret_cast<const s16x8*>(VF);

    f32x16 O0 = {}, O1 = {};
    float lsum = 0.f;

    auto process = [&](const s16x8* kh, const s16x8* kl, const s16x8* vv) {
        f32x16 S = {};
#pragma unroll
        for (int s = 0; s < 4; ++s) S = MFMA32(kh[s], qh[s], S);
#pragma unroll
        for (int s = 0; s < 4; ++s) S = MFMA32(kh[s], ql[s], S);
#pragma unroll
        for (int s = 0; s < 4; ++s) S = MFMA32(kl[s], qh[s], S);

        float e[16];
#pragma unroll
        for (int r = 0; r < 16; ++r) e[r] = __expf(S[r]);
        lsum += (((e[0] + e[1]) + (e[2] + e[3])) + ((e[4] + e[5]) + (e[6] + e[7])))
              + (((e[8] + e[9]) + (e[10] + e[11])) + ((e[12] + e[13]) + (e[14] + e[15])));

        unsigned int pk[8];
#pragma unroll
        for (int j2 = 0; j2 < 8; ++j2)
            pk[j2] = (__float_as_uint(e[2 * j2]) >> 16) | (__float_as_uint(e[2 * j2 + 1]) & 0xFFFF0000u);

        unsigned int x[8];
#pragma unroll
        for (int j2 = 0; j2 < 8; ++j2) x[j2] = (unsigned int)__shfl_xor((int)pk[j2], 32, 64);

        union { unsigned int u[4]; s16x8 v; } P0, P1;
        P0.u[0] = h ? x[2]  : pk[0];
        P0.u[1] = h ? x[3]  : pk[1];
        P0.u[2] = h ? pk[2] : x[0];
        P0.u[3] = h ? pk[3] : x[1];
        P1.u[0] = h ? x[6]  : pk[4];
        P1.u[1] = h ? x[7]  : pk[5];
        P1.u[2] = h ? pk[6] : x[4];
        P1.u[3] = h ? pk[7] : x[5];

        O0 = MFMA32(vv[0], P0.v, O0);
        O0 = MFMA32(vv[1], P1.v, O0);
        O1 = MFMA32(vv[2], P0.v, O1);
        O1 = MFMA32(vv[3], P1.v, O1);
    };

    for (int it = 0; it < 16; it += 2) {
        const int jtA = g * 16 + it;
        const int jtB = jtA + 1;
        s16x8 khA[4], klA[4], vA[4], khB[4], klB[4], vB[4];
#pragma unroll
        for (int s = 0; s < 4; ++s) {
            khA[s] = KH[(jtA * 4 + s) * 64 + lane];
            klA[s] = KL[(jtA * 4 + s) * 64 + lane];
            vA[s]  = VV[(jtA * 4 + s) * 64 + lane];
            khB[s] = KH[(jtB * 4 + s) * 64 + lane];
            klB[s] = KL[(jtB * 4 + s) * 64 + lane];
            vB[s]  = VV[(jtB * 4 + s) * 64 + lane];
        }
        process(khA, klA, vA);
        process(khB, klB, vB);
    }

    lsum += __shfl_xor(lsum, 32, 64);

    const size_t qg = (size_t)g * SA_N + q0 + q32;
#pragma unroll
    for (int rg = 0; rg < 4; ++rg) {
        const int d0 = 8 * rg + 4 * h;
        uint2 s0, s1;
        s0.x = (unsigned int)f2bf_rn(O0[4 * rg + 0]) | ((unsigned int)f2bf_rn(O0[4 * rg + 1]) << 16);
        s0.y = (unsigned int)f2bf_rn(O0[4 * rg + 2]) | ((unsigned int)f2bf_rn(O0[4 * rg + 3]) << 16);
        s1.x = (unsigned int)f2bf_rn(O1[4 * rg + 0]) | ((unsigned int)f2bf_rn(O1[4 * rg + 1]) << 16);
        s1.y = (unsigned int)f2bf_rn(O1[4 * rg + 2]) | ((unsigned int)f2bf_rn(O1[4 * rg + 3]) << 16);
        *(uint2*)(Opart + qg * 64 + d0)      = s0;
        *(uint2*)(Opart + qg * 64 + d0 + 32) = s1;
    }
    if (h == 0) Lpart[qg] = lsum;
}

// ---- Kernel C: combine 16 partials, normalize ----
__global__ __launch_bounds__(256) void combine_kernel(
    const unsigned short* __restrict__ Opart, const float* __restrict__ Lpart,
    float* __restrict__ out)
{
    const int tid = blockIdx.x * 256 + threadIdx.x;   // 0..262143
    const int q  = tid >> 5;
    const int dp = tid & 31;
    const unsigned int* OP = (const unsigned int*)Opart;
    float s0 = 0.f, s1 = 0.f, lt = 0.f;
#pragma unroll
    for (int g = 0; g < G_SPL; ++g) {
        const unsigned int v = OP[((size_t)g * SA_N + q) * 32 + dp];
        s0 += __uint_as_float(v << 16);
        s1 += __uint_as_float(v & 0xFFFF0000u);
        lt += Lpart[(size_t)g * SA_N + q];
    }
    float2 r = { s0 / lt, s1 / lt };
    *(float2*)&out[(size_t)q * 64 + dp * 2] = r;
}

extern "C" void kernel_launch(void* const* d_in, const int* in_sizes, int n_in,
                              void* d_out, int out_size, void* d_ws, size_t ws_size,
                              hipStream_t stream) {
    const float* input = (const float*)d_in[0];
    const float* Wq    = (const float*)d_in[1];
    const float* bq    = (const float*)d_in[2];
    const float* Wk    = (const float*)d_in[3];
    const float* bk    = (const float*)d_in[4];
    const float* Wv    = (const float*)d_in[5];
    const float* bv    = (const float*)d_in[6];
    float* out = (float*)d_out;

    const size_t SEG = (size_t)SA_N * 64;
    unsigned short* WHI  = (unsigned short*)d_ws;
    unsigned short* WLO  = WHI  + 98304;
    unsigned short* Qhi  = WLO  + 98304;
    unsigned short* Qlo  = Qhi  + SEG;
    unsigned short* KhiF = Qlo  + SEG;
    unsigned short* KloF = KhiF + SEG;
    unsigned short* VF   = KloF + SEG;
    unsigned short* Opart = VF  + SEG;               // G_SPL*N*64 bf16 = 16 MB
    float*          Lpart = (float*)(Opart + (size_t)G_SPL * SA_N * 64);  // 512 KB
    // total ws use ~23 MB

    wconv_kernel<<<384, 256, 0, stream>>>(Wq, Wk, Wv, WHI, WLO);
    qkv_kernel<<<256, 512, 0, stream>>>(input, WHI, WLO, bq, bk, bv,
                                        Qhi, Qlo, KhiF, KloF, VF);
    attn_kernel<<<64 * G_SPL, 256, 0, stream>>>(Qhi, Qlo, KhiF, KloF, VF, Opart, Lpart);
    combine_kernel<<<1024, 256, 0, stream>>>(Opart, Lpart, out);
}

// Round 6
// 141.450 us; speedup vs baseline: 1.4579x; 1.4579x over previous
//
#include <hip/hip_runtime.h>
#include <math.h>

#define SA_N   8192
#define SA_IN  512
#define SA_D   64
#define G_SPL  16

typedef short s16x8 __attribute__((ext_vector_type(8)));
typedef float f32x16 __attribute__((ext_vector_type(16)));

#define MFMA32(A, B, C) __builtin_amdgcn_mfma_f32_32x32x16_bf16((A), (B), (C), 0, 0, 0)

static __device__ __forceinline__ unsigned short f2bf_rn(float x) {
    unsigned int u = __float_as_uint(x);
    unsigned int r = (u + 0x7FFFu + ((u >> 16) & 1u)) >> 16;
    return (unsigned short)r;
}

static __device__ __forceinline__ void trunc_split(float f, unsigned short* hi, unsigned short* lo) {
    unsigned int u = __float_as_uint(f);
    *hi = (unsigned short)(u >> 16);
    float lf = f - __uint_as_float(u & 0xFFFF0000u);
    *lo = (unsigned short)(__float_as_uint(lf) >> 16);
}

static __device__ __forceinline__ void split8(const float4 a, const float4 b, s16x8* xh, s16x8* xl) {
    union { unsigned int u[4]; s16x8 v; } H, L;
    const float f[8] = {a.x, a.y, a.z, a.w, b.x, b.y, b.z, b.w};
#pragma unroll
    for (int p = 0; p < 4; ++p) {
        const unsigned int u0 = __float_as_uint(f[2 * p]);
        const unsigned int u1 = __float_as_uint(f[2 * p + 1]);
        H.u[p] = (u0 >> 16) | (u1 & 0xFFFF0000u);
        const float l0 = f[2 * p]     - __uint_as_float(u0 & 0xFFFF0000u);
        const float l1 = f[2 * p + 1] - __uint_as_float(u1 & 0xFFFF0000u);
        L.u[p] = (__float_as_uint(l0) >> 16) | (__float_as_uint(l1) & 0xFFFF0000u);
    }
    *xh = H.v; *xl = L.v;
}

// ---- Kernel 0: W (fp32) -> A-fragment-ordered bf16 hi/lo ----
__global__ __launch_bounds__(256) void wconv_kernel(
    const float* __restrict__ Wq, const float* __restrict__ Wk, const float* __restrict__ Wv,
    unsigned short* __restrict__ WHI, unsigned short* __restrict__ WLO)
{
    const int idx  = blockIdx.x * 256 + threadIdx.x;
    const int mat  = idx >> 15;
    const int rem  = idx & 32767;
    const int mt   = rem >> 14;
    const int ks   = (rem >> 9) & 31;
    const int lane = (rem >> 3) & 63;
    const int i    = rem & 7;
    const int o = mt * 32 + (lane & 31);
    const int k = ks * 16 + (lane >> 5) * 8 + i;
    const float* W = (mat == 0) ? Wq : (mat == 1 ? Wk : Wv);
    unsigned short hi, lo;
    trunc_split(W[o * SA_IN + k], &hi, &lo);
    WHI[idx] = hi; WLO[idx] = lo;
}

// ---- Kernel A: QKV via bf16x3 MFMA, 8 waves, 8-way k-split ----
// grid 256, block 512. Block = 32 rows (tile jt). Wave w handles ks = w*4..w*4+3.
// Epilogue v2: per-set LDS combine -> fragment-order scatter into LDS staging
// (each block's Q/K/V fragment regions are contiguous 4KB spans) -> one barrier
// -> cooperative dwordx4 coalesced stores. Replaces ~6K scattered 2B global
// stores per block (R3/R4 write-combining pathology) with 1280 16B stores.
__global__ __launch_bounds__(512, 2) void qkv_kernel(
    const float* __restrict__ in,
    const unsigned short* __restrict__ WHI, const unsigned short* __restrict__ WLO,
    const float* __restrict__ bq, const float* __restrict__ bk, const float* __restrict__ bv,
    unsigned short* __restrict__ Qhi, unsigned short* __restrict__ Qlo,
    unsigned short* __restrict__ KhiF, unsigned short* __restrict__ KloF,
    unsigned short* __restrict__ VF)
{
    __shared__ float cbuf[8][64][20];                         // 40 KB
    __shared__ __align__(16) unsigned short stage[5 * 2048];  // 20 KB: qhi,qlo,khi,klo,v
    const int t    = threadIdx.x;
    const int w    = t >> 6;        // 0..7
    const int lane = t & 63;
    const int h    = lane >> 5;
    const int q32  = lane & 31;
    const int jt   = blockIdx.x;
    const int rows0 = jt * 32;

    const s16x8* WH8 = (const s16x8*)WHI;
    const s16x8* WL8 = (const s16x8*)WLO;

    f32x16 acc[6] = {};   // q0,q1,k0,k1,v0,v1

#pragma unroll
    for (int ksl = 0; ksl < 4; ++ksl) {
        const int ks = (w << 2) + ksl;
        const float* xp = in + (size_t)(rows0 + q32) * SA_IN + ks * 16 + h * 8;
        const float4 xa = *(const float4*)xp;
        const float4 xb = *(const float4*)(xp + 4);
        s16x8 xh, xl;
        split8(xa, xb, &xh, &xl);
        const int fb = ks * 64 + lane;
#pragma unroll
        for (int mt = 0; mt < 2; ++mt) {
            s16x8 ah = WH8[(0 + mt) * 2048 + fb];
            s16x8 al = WL8[(0 + mt) * 2048 + fb];
            acc[mt] = MFMA32(ah, xh, acc[mt]);
            acc[mt] = MFMA32(ah, xl, acc[mt]);
            acc[mt] = MFMA32(al, xh, acc[mt]);
            ah = WH8[(2 + mt) * 2048 + fb];
            al = WL8[(2 + mt) * 2048 + fb];
            acc[2 + mt] = MFMA32(ah, xh, acc[2 + mt]);
            acc[2 + mt] = MFMA32(ah, xl, acc[2 + mt]);
            acc[2 + mt] = MFMA32(al, xh, acc[2 + mt]);
            ah = WH8[(4 + mt) * 2048 + fb];
            acc[4 + mt] = MFMA32(ah, xh, acc[4 + mt]);   // v: 1-term suffices
        }
    }

#pragma unroll
    for (int s = 0; s < 6; ++s) {
        __syncthreads();
#pragma unroll
        for (int rg = 0; rg < 4; ++rg) {
            float4 vv = { acc[s][4 * rg + 0], acc[s][4 * rg + 1],
                          acc[s][4 * rg + 2], acc[s][4 * rg + 3] };
            *(float4*)&cbuf[w][lane][4 * rg] = vv;
        }
        __syncthreads();
        if (w == s) {
            const int mat = s >> 1;
            const int mt  = s & 1;
            float c[16];
#pragma unroll
            for (int rg = 0; rg < 4; ++rg) {
                float4 acc4 = *(const float4*)&cbuf[0][lane][4 * rg];
#pragma unroll
                for (int p = 1; p < 8; ++p) {
                    const float4 pp = *(const float4*)&cbuf[p][lane][4 * rg];
                    acc4.x += pp.x; acc4.y += pp.y; acc4.z += pp.z; acc4.w += pp.w;
                }
                c[4 * rg + 0] = acc4.x; c[4 * rg + 1] = acc4.y;
                c[4 * rg + 2] = acc4.z; c[4 * rg + 3] = acc4.w;
            }
            const float* B = (mat == 0) ? bq : (mat == 1 ? bk : bv);
#pragma unroll
            for (int r = 0; r < 16; ++r) {
                const int o = mt * 32 + (r & 3) + 8 * (r >> 2) + 4 * h;
                const float val = c[r] + B[o];
                if (mat == 0) {
                    unsigned short hi, lo;
                    trunc_split(val, &hi, &lo);
                    stage[0    + q32 * 64 + o] = hi;
                    stage[2048 + q32 * 64 + o] = lo;
                } else if (mat == 1) {
                    unsigned short hi, lo;
                    trunc_split(val, &hi, &lo);
                    const int kl_ = ((o >> 4) * 64 + ((o >> 3) & 1) * 32 + q32) * 8 + (o & 7);
                    stage[4096 + kl_] = hi;
                    stage[6144 + kl_] = lo;
                } else {
                    const int vl_ = ((o >> 5) * 2 + ((q32 >> 4) & 1)) * 512
                                  + ((q32 >> 3) & 1) * 256 + (o & 31) * 8 + (q32 & 7);
                    stage[8192 + vl_] = f2bf_rn(val);
                }
            }
        }
    }
    __syncthreads();

    // cooperative coalesced store: 5 regions x 256 uint4
    {
        const uint4* st4 = (const uint4*)stage;
        for (int i = t; i < 1280; i += 512) {
            const int r = i >> 8;
            const int off = (i & 255) * 8;   // ushort offset within region
            unsigned short* dst =
                (r == 0) ? Qhi  + (size_t)rows0 * 64 :
                (r == 1) ? Qlo  + (size_t)rows0 * 64 :
                (r == 2) ? KhiF + (size_t)jt * 2048 :
                (r == 3) ? KloF + (size_t)jt * 2048 :
                           VF   + (size_t)jt * 2048;
            *(uint4*)(dst + off) = st4[i];
        }
    }
}

// ---- Kernel B: MFMA flash attention, key-split G=16 ----
// grid 1024 = 64 qb x 16 g. launch_bounds(256,2): VGPR ~92 (NO 4-wave cap —
// R4's (256,4) forced VGPR 64 -> massive spills, FETCH 9.7->121MB, 2.3x slower).
// At VGPR 92 HW fits 5 waves/SIMD; grid gives 4 blocks/CU. Zero LDS, no barriers.
__global__ __launch_bounds__(256, 2) void attn_kernel(
    const unsigned short* __restrict__ Qhi, const unsigned short* __restrict__ Qlo,
    const unsigned short* __restrict__ KhiF, const unsigned short* __restrict__ KloF,
    const unsigned short* __restrict__ VF,
    unsigned short* __restrict__ Opart, float* __restrict__ Lpart)
{
    const int t    = threadIdx.x;
    const int w    = t >> 6;
    const int lane = t & 63;
    const int h    = lane >> 5;
    const int q32  = lane & 31;
    const int qb   = blockIdx.x >> 4;
    const int g    = blockIdx.x & 15;
    const int q0   = (qb * 4 + w) * 32;

    s16x8 qh[4], ql[4];
#pragma unroll
    for (int s = 0; s < 4; ++s) {
        const size_t off = (size_t)(q0 + q32) * 64 + s * 16 + h * 8;
        qh[s] = *reinterpret_cast<const s16x8*>(Qhi + off);
        ql[s] = *reinterpret_cast<const s16x8*>(Qlo + off);
    }

    const s16x8* KH = reinterpret_cast<const s16x8*>(KhiF);
    const s16x8* KL = reinterpret_cast<const s16x8*>(KloF);
    const s16x8* VV = reinterpret_cast<const s16x8*>(VF);

    f32x16 O0 = {}, O1 = {};
    float lsum = 0.f;

    auto process = [&](const s16x8* kh, const s16x8* kl, const s16x8* vv) {
        f32x16 S = {};
#pragma unroll
        for (int s = 0; s < 4; ++s) S = MFMA32(kh[s], qh[s], S);
#pragma unroll
        for (int s = 0; s < 4; ++s) S = MFMA32(kh[s], ql[s], S);
#pragma unroll
        for (int s = 0; s < 4; ++s) S = MFMA32(kl[s], qh[s], S);

        float e[16];
#pragma unroll
        for (int r = 0; r < 16; ++r) e[r] = __expf(S[r]);
        lsum += (((e[0] + e[1]) + (e[2] + e[3])) + ((e[4] + e[5]) + (e[6] + e[7])))
              + (((e[8] + e[9]) + (e[10] + e[11])) + ((e[12] + e[13]) + (e[14] + e[15])));

        unsigned int pk[8];
#pragma unroll
        for (int j2 = 0; j2 < 8; ++j2)
            pk[j2] = (__float_as_uint(e[2 * j2]) >> 16) | (__float_as_uint(e[2 * j2 + 1]) & 0xFFFF0000u);

        unsigned int x[8];
#pragma unroll
        for (int j2 = 0; j2 < 8; ++j2) x[j2] = (unsigned int)__shfl_xor((int)pk[j2], 32, 64);

        union { unsigned int u[4]; s16x8 v; } P0, P1;
        P0.u[0] = h ? x[2]  : pk[0];
        P0.u[1] = h ? x[3]  : pk[1];
        P0.u[2] = h ? pk[2] : x[0];
        P0.u[3] = h ? pk[3] : x[1];
        P1.u[0] = h ? x[6]  : pk[4];
        P1.u[1] = h ? x[7]  : pk[5];
        P1.u[2] = h ? pk[6] : x[4];
        P1.u[3] = h ? pk[7] : x[5];

        O0 = MFMA32(vv[0], P0.v, O0);
        O0 = MFMA32(vv[1], P1.v, O0);
        O1 = MFMA32(vv[2], P0.v, O1);
        O1 = MFMA32(vv[3], P1.v, O1);
    };

    for (int it = 0; it < 16; it += 2) {
        const int jtA = g * 16 + it;
        const int jtB = jtA + 1;
        s16x8 khA[4], klA[4], vA[4], khB[4], klB[4], vB[4];
#pragma unroll
        for (int s = 0; s < 4; ++s) {
            khA[s] = KH[(jtA * 4 + s) * 64 + lane];
            klA[s] = KL[(jtA * 4 + s) * 64 + lane];
            vA[s]  = VV[(jtA * 4 + s) * 64 + lane];
            khB[s] = KH[(jtB * 4 + s) * 64 + lane];
            klB[s] = KL[(jtB * 4 + s) * 64 + lane];
            vB[s]  = VV[(jtB * 4 + s) * 64 + lane];
        }
        process(khA, klA, vA);
        process(khB, klB, vB);
    }

    lsum += __shfl_xor(lsum, 32, 64);

    const size_t qg = (size_t)g * SA_N + q0 + q32;
#pragma unroll
    for (int rg = 0; rg < 4; ++rg) {
        const int d0 = 8 * rg + 4 * h;
        uint2 s0, s1;
        s0.x = (unsigned int)f2bf_rn(O0[4 * rg + 0]) | ((unsigned int)f2bf_rn(O0[4 * rg + 1]) << 16);
        s0.y = (unsigned int)f2bf_rn(O0[4 * rg + 2]) | ((unsigned int)f2bf_rn(O0[4 * rg + 3]) << 16);
        s1.x = (unsigned int)f2bf_rn(O1[4 * rg + 0]) | ((unsigned int)f2bf_rn(O1[4 * rg + 1]) << 16);
        s1.y = (unsigned int)f2bf_rn(O1[4 * rg + 2]) | ((unsigned int)f2bf_rn(O1[4 * rg + 3]) << 16);
        *(uint2*)(Opart + qg * 64 + d0)      = s0;
        *(uint2*)(Opart + qg * 64 + d0 + 32) = s1;
    }
    if (h == 0) Lpart[qg] = lsum;
}

// ---- Kernel C: combine 16 partials, normalize ----
__global__ __launch_bounds__(256) void combine_kernel(
    const unsigned short* __restrict__ Opart, const float* __restrict__ Lpart,
    float* __restrict__ out)
{
    const int tid = blockIdx.x * 256 + threadIdx.x;   // 0..262143
    const int q  = tid >> 5;
    const int dp = tid & 31;
    const unsigned int* OP = (const unsigned int*)Opart;
    float s0 = 0.f, s1 = 0.f, lt = 0.f;
#pragma unroll
    for (int g = 0; g < G_SPL; ++g) {
        const unsigned int v = OP[((size_t)g * SA_N + q) * 32 + dp];
        s0 += __uint_as_float(v << 16);
        s1 += __uint_as_float(v & 0xFFFF0000u);
        lt += Lpart[(size_t)g * SA_N + q];
    }
    float2 r = { s0 / lt, s1 / lt };
    *(float2*)&out[(size_t)q * 64 + dp * 2] = r;
}

extern "C" void kernel_launch(void* const* d_in, const int* in_sizes, int n_in,
                              void* d_out, int out_size, void* d_ws, size_t ws_size,
                              hipStream_t stream) {
    const float* input = (const float*)d_in[0];
    const float* Wq    = (const float*)d_in[1];
    const float* bq    = (const float*)d_in[2];
    const float* Wk    = (const float*)d_in[3];
    const float* bk    = (const float*)d_in[4];
    const float* Wv    = (const float*)d_in[5];
    const float* bv    = (const float*)d_in[6];
    float* out = (float*)d_out;

    const size_t SEG = (size_t)SA_N * 64;
    unsigned short* WHI  = (unsigned short*)d_ws;
    unsigned short* WLO  = WHI  + 98304;
    unsigned short* Qhi  = WLO  + 98304;
    unsigned short* Qlo  = Qhi  + SEG;
    unsigned short* KhiF = Qlo  + SEG;
    unsigned short* KloF = KhiF + SEG;
    unsigned short* VF   = KloF + SEG;
    unsigned short* Opart = VF  + SEG;               // G_SPL*N*64 bf16 = 16 MB
    float*          Lpart = (float*)(Opart + (size_t)G_SPL * SA_N * 64);  // 512 KB

    wconv_kernel<<<384, 256, 0, stream>>>(Wq, Wk, Wv, WHI, WLO);
    qkv_kernel<<<256, 512, 0, stream>>>(input, WHI, WLO, bq, bk, bv,
                                        Qhi, Qlo, KhiF, KloF, VF);
    attn_kernel<<<64 * G_SPL, 256, 0, stream>>>(Qhi, Qlo, KhiF, KloF, VF, Opart, Lpart);
    combine_kernel<<<1024, 256, 0, stream>>>(Opart, Lpart, out);
}